// Round 6
// baseline (462.119 us; speedup 1.0000x reference)
//
#include <hip/hip_runtime.h>
#include <hip/hip_bf16.h>

#define S 4
#define N 32768
#define D 256
#define KSEG 512
#define NH 4
#define HD 64
#define FF 1024

typedef __attribute__((ext_vector_type(8))) short short8;
typedef __attribute__((ext_vector_type(4))) float f32x4;
typedef __attribute__((ext_vector_type(4))) unsigned int u32x4;
typedef __attribute__((ext_vector_type(2))) unsigned int u32x2;

__device__ __forceinline__ unsigned short f2bf(float f) {
  union { __hip_bfloat16 h; unsigned short u; } cv;
  cv.h = __float2bfloat16(f);
  return cv.u;
}

__device__ __forceinline__ float gelu_f(float x) {
  return 0.5f * x * (1.0f + erff(x * 0.70710678118654752440f));
}

__device__ __forceinline__ float wave_reduce_sum(float v) {
  #pragma unroll
  for (int o = 32; o > 0; o >>= 1) v += __shfl_xor(v, o, 64);
  return v;
}

// ---------------- Phase A: counting sort by patch id ----------------
__global__ __launch_bounds__(256) void hist_kernel(
    const int* __restrict__ pids, int* __restrict__ histc)
{
  __shared__ int h[KSEG];
  int b = blockIdx.x, t = threadIdx.x;
  int s = b >> 4, c = b & 15;
  for (int i = t; i < KSEG; i += 256) h[i] = 0;
  __syncthreads();
  const int* p = pids + s * N + c * 2048;
  for (int i = t; i < 2048; i += 256) atomicAdd(&h[p[i]], 1);
  __syncthreads();
  for (int i = t; i < KSEG; i += 256) histc[(s * 16 + c) * KSEG + i] = h[i];
}

__global__ __launch_bounds__(256) void prefix_kernel(
    int* __restrict__ histc, int* __restrict__ segstart,
    int* __restrict__ cnti, float* __restrict__ counts)
{
  __shared__ int h[16 * KSEG];   // 32 KB
  __shared__ int sc[KSEG];
  __shared__ int sa[KSEG], sb[KSEG];
  int s = blockIdx.x, t = threadIdx.x;
  for (int i = t; i < 16 * KSEG; i += 256) h[i] = histc[s * 16 * KSEG + i];
  __syncthreads();
  #pragma unroll
  for (int u = 0; u < 2; u++) {
    int bin = t + u * 256;
    int cc = 0;
    #pragma unroll
    for (int c = 0; c < 16; c++) cc += h[c * KSEG + bin];
    sc[bin] = cc;
    sa[bin] = cc;
  }
  __syncthreads();
  int* src = sa; int* dst = sb;
  for (int off = 1; off < KSEG; off <<= 1) {
    #pragma unroll
    for (int u = 0; u < 2; u++) {
      int bin = t + u * 256;
      int v = src[bin];
      if (bin >= off) v += src[bin - off];
      dst[bin] = v;
    }
    __syncthreads();
    int* tmp = src; src = dst; dst = tmp;
  }
  #pragma unroll
  for (int u = 0; u < 2; u++) {
    int bin = t + u * 256;
    int cc = sc[bin];
    int excl = src[bin] - cc;
    segstart[s * KSEG + bin] = excl;
    cnti[s * KSEG + bin] = cc;
    counts[s * KSEG + bin] = (float)cc;
    int run = excl;
    #pragma unroll
    for (int c = 0; c < 16; c++) {
      int v = h[c * KSEG + bin];
      h[c * KSEG + bin] = run;
      run += v;
    }
  }
  __syncthreads();
  for (int i = t; i < 16 * KSEG; i += 256) histc[s * 16 * KSEG + i] = h[i];
}

__global__ __launch_bounds__(256) void scatter_kernel(
    const int* __restrict__ pids, const int* __restrict__ histc,
    int* __restrict__ order)
{
  __shared__ int offs[KSEG];
  int b = blockIdx.x, t = threadIdx.x;
  int s = b >> 4, c = b & 15;
  for (int i = t; i < KSEG; i += 256) offs[i] = histc[(s * 16 + c) * KSEG + i];
  __syncthreads();
  const int* p = pids + s * N + c * 2048;
  for (int i = t; i < 2048; i += 256) {
    int pid = p[i];
    int pos = atomicAdd(&offs[pid], 1);
    order[s * N + pos] = s * N + c * 2048 + i;
  }
}

// gather-reduce: TWO waves per segment (halves tail imbalance). grid 1024.
__global__ __launch_bounds__(256) void pool_gather(
    const float* __restrict__ H, const int* __restrict__ order,
    const int* __restrict__ segstart, const int* __restrict__ cnti,
    float* __restrict__ xw)
{
  __shared__ float pbuf[4][256];
  int tid = threadIdx.x;
  int w = tid >> 6, lane = tid & 63;
  int seg = blockIdx.x * 2 + (w >> 1);
  int half = w & 1;
  int s = seg >> 9;
  int st = segstart[seg], cn = cnti[seg];
  int en = st + cn;
  const int* ord = order + (size_t)s * N;
  int c4 = lane << 2;
  f32x4 a0 = {0,0,0,0}, a1 = {0,0,0,0}, a2 = {0,0,0,0}, a3 = {0,0,0,0};
  f32x4 a4 = {0,0,0,0}, a5 = {0,0,0,0}, a6 = {0,0,0,0}, a7 = {0,0,0,0};
  int i = st + half;
  for (; i + 14 < en; i += 16) {
    int r0 = ord[i + 0], r1 = ord[i + 2], r2 = ord[i + 4], r3 = ord[i + 6];
    int r4 = ord[i + 8], r5 = ord[i + 10], r6 = ord[i + 12], r7 = ord[i + 14];
    a0 += *(const f32x4*)(H + (size_t)r0 * 256 + c4);
    a1 += *(const f32x4*)(H + (size_t)r1 * 256 + c4);
    a2 += *(const f32x4*)(H + (size_t)r2 * 256 + c4);
    a3 += *(const f32x4*)(H + (size_t)r3 * 256 + c4);
    a4 += *(const f32x4*)(H + (size_t)r4 * 256 + c4);
    a5 += *(const f32x4*)(H + (size_t)r5 * 256 + c4);
    a6 += *(const f32x4*)(H + (size_t)r6 * 256 + c4);
    a7 += *(const f32x4*)(H + (size_t)r7 * 256 + c4);
  }
  for (; i < en; i += 2) {
    int r = ord[i];
    a0 += *(const f32x4*)(H + (size_t)r * 256 + c4);
  }
  f32x4 ssum = ((a0 + a1) + (a2 + a3)) + ((a4 + a5) + (a6 + a7));
  *(f32x4*)&pbuf[w][c4] = ssum;
  __syncthreads();
  if (half == 0) {
    f32x4 tot = *(f32x4*)&pbuf[w][c4];
    tot += *(f32x4*)&pbuf[w + 1][c4];
    float inv = 1.f / fmaxf((float)cn, 1.f);
    tot = tot * inv;
    *(f32x4*)(xw + (size_t)seg * 256 + c4) = tot;
  }
}

// y = LN(x). grid 2048 rows
__global__ __launch_bounds__(256) void pool_ln_kernel(
    const float* __restrict__ xw,
    const float* __restrict__ g, const float* __restrict__ b,
    float* __restrict__ yw)
{
  int row = blockIdx.x, t = threadIdx.x;
  float v = xw[row * 256 + t];
  float s1 = wave_reduce_sum(v);
  float s2 = wave_reduce_sum(v * v);
  __shared__ float a1[4], a2[4];
  int w = t >> 6;
  if ((t & 63) == 0) { a1[w] = s1; a2[w] = s2; }
  __syncthreads();
  float ts1 = a1[0] + a1[1] + a1[2] + a1[3];
  float ts2 = a2[0] + a2[1] + a2[2] + a2[3];
  float mu = ts1 * (1.f / 256.f);
  float var = ts2 * (1.f / 256.f) - mu * mu;
  yw[row * 256 + t] = (v - mu) * rsqrtf(var + 1e-5f) * g[t] + b[t];
}

__global__ __launch_bounds__(256) void ln_kernel(
    const float* __restrict__ in, float* __restrict__ outp,
    const float* __restrict__ g, const float* __restrict__ b)
{
  int row = blockIdx.x, t = threadIdx.x;
  float v = in[row * 256 + t];
  float s1 = wave_reduce_sum(v);
  float s2 = wave_reduce_sum(v * v);
  __shared__ float a1[4], a2[4];
  int w = t >> 6;
  if ((t & 63) == 0) { a1[w] = s1; a2[w] = s2; }
  __syncthreads();
  float ts1 = a1[0] + a1[1] + a1[2] + a1[3];
  float ts2 = a2[0] + a2[1] + a2[2] + a2[3];
  float mu = ts1 * (1.f / 256.f);
  float var = ts2 * (1.f / 256.f) - mu * mu;
  outp[row * 256 + t] = (v - mu) * rsqrtf(var + 1e-5f) * g[t] + b[t];
}

// QKV projections + phi + mask. 4-row blocks: grid (512, 3)
__global__ __launch_bounds__(256) void qkv_kernel(
    const float* __restrict__ y, const float* __restrict__ counts,
    const float* __restrict__ Wq, const float* __restrict__ bq,
    const float* __restrict__ Wk, const float* __restrict__ bk,
    const float* __restrict__ Wv, const float* __restrict__ bv,
    float* __restrict__ qo, float* __restrict__ ko, float* __restrict__ vo)
{
  int m = blockIdx.y;
  const float* W = (m == 0) ? Wq : ((m == 1) ? Wk : Wv);
  const float* bias = (m == 0) ? bq : ((m == 1) ? bk : bv);
  float* outp = (m == 0) ? qo : ((m == 1) ? ko : vo);
  int rb = blockIdx.x, col = threadIdx.x;
  __shared__ float yl[4][256];
  for (int i = threadIdx.x; i < 4 * 256; i += 256)
    yl[i >> 8][i & 255] = y[(rb * 4 + (i >> 8)) * 256 + (i & 255)];
  __syncthreads();
  float acc[4] = {0, 0, 0, 0};
  #pragma unroll 8
  for (int kk = 0; kk < 256; kk++) {
    float wv = W[kk * 256 + col];
    #pragma unroll
    for (int r = 0; r < 4; r++) acc[r] += yl[r][kk] * wv;
  }
  #pragma unroll
  for (int r = 0; r < 4; r++) {
    int row = rb * 4 + r;
    float tv = acc[r] + bias[col];
    if (m <= 1) tv = (tv > 0.f) ? (tv + 1.f) : expf(tv);   // phi = elu+1
    if (m >= 1) tv *= (counts[row] > 0.f) ? 1.f : 0.f;     // mask on k,v
    outp[row * 256 + col] = tv;
  }
}

// kv[s,h,d,e] = sum_k k*v ; ksum[s,h,d]. single-barrier batched. grid 128
__global__ __launch_bounds__(256) void kv_kernel(
    const float* __restrict__ kw, const float* __restrict__ vw,
    float* __restrict__ kvb, float* __restrict__ ksb)
{
  int b = blockIdx.x, t = threadIdx.x;
  int s = b / (NH * 8), h = (b / 8) % NH, ck = b & 7;
  __shared__ float kl[64 * 64];   // 16 KB
  __shared__ float vl[64 * 64];   // 16 KB
  for (int i = t; i < 4096; i += 256) {
    int kk = i >> 6, d = i & 63;
    size_t rowb = ((size_t)(s * KSEG + ck * 64 + kk) * NH + h) * HD + d;
    kl[i] = kw[rowb];
    vl[i] = vw[rowb];
  }
  __syncthreads();
  int d = t & 63, eb = (t >> 6) * 16;
  f32x4 a4[4];
  #pragma unroll
  for (int j = 0; j < 4; j++) a4[j] = (f32x4){0.f, 0.f, 0.f, 0.f};
  float acck = 0.f;
  #pragma unroll 4
  for (int kk = 0; kk < 64; kk++) {
    float kd = kl[kk * 64 + d];
    acck += kd;
    #pragma unroll
    for (int j = 0; j < 4; j++) {
      f32x4 vv = *(const f32x4*)&vl[kk * 64 + eb + j * 4];
      a4[j] += kd * vv;
    }
  }
  #pragma unroll
  for (int j = 0; j < 4; j++)
    #pragma unroll
    for (int e = 0; e < 4; e++)
      atomicAdd(&kvb[(((size_t)(s * NH + h)) * HD + d) * HD + eb + j * 4 + e], a4[j][e]);
  if (t < 64) atomicAdd(&ksb[(s * NH + h) * HD + t], acck);
}

// a = num/den per row, register-tiled. grid 256 blocks
__global__ __launch_bounds__(256) void attn_kernel(
    const float* __restrict__ qw, const float* __restrict__ kvb,
    const float* __restrict__ ksb, float* __restrict__ aw)
{
  __shared__ float kvl[64 * 64];   // 16 KB
  __shared__ float ksl[64];
  __shared__ float ql[32 * 64];    // 8 KB
  int t = threadIdx.x, b = blockIdx.x;
  int sh = b >> 4, rb = b & 15;
  int s = sh >> 2, h = sh & 3;
  for (int i = t; i < 4096; i += 256) kvl[i] = kvb[sh * 4096 + i];
  if (t < 64) ksl[t] = ksb[sh * 64 + t];
  for (int i = t; i < 2048; i += 256) {
    int r = i >> 6, d = i & 63;
    ql[i] = qw[((size_t)(s * KSEG + rb * 32 + r)) * 256 + h * 64 + d];
  }
  __syncthreads();
  int e = t & 63, rg = t >> 6;
  float num[8], den[8];
  #pragma unroll
  for (int r = 0; r < 8; r++) { num[r] = 0.f; den[r] = 0.f; }
  #pragma unroll 4
  for (int d4 = 0; d4 < 64; d4 += 4) {
    float4 ks4 = *(const float4*)&ksl[d4];
    float kv0 = kvl[(d4 + 0) * 64 + e];
    float kv1 = kvl[(d4 + 1) * 64 + e];
    float kv2 = kvl[(d4 + 2) * 64 + e];
    float kv3 = kvl[(d4 + 3) * 64 + e];
    #pragma unroll
    for (int r = 0; r < 8; r++) {
      float4 q4 = *(const float4*)&ql[(rg * 8 + r) * 64 + d4];
      num[r] += q4.x * kv0 + q4.y * kv1 + q4.z * kv2 + q4.w * kv3;
      den[r] += q4.x * ks4.x + q4.y * ks4.y + q4.z * ks4.z + q4.w * ks4.w;
    }
  }
  #pragma unroll
  for (int r = 0; r < 8; r++) {
    int row = rb * 32 + rg * 8 + r;
    aw[((size_t)(s * KSEG + row)) * 256 + h * 64 + e] = num[r] / (den[r] + 1e-6f);
  }
}

// x2 = x + a@Wo + bo. 4-row blocks: grid 512
__global__ __launch_bounds__(256) void oproj_kernel(
    const float* __restrict__ aw, const float* __restrict__ x,
    const float* __restrict__ Wo, const float* __restrict__ bo,
    float* __restrict__ x2)
{
  int rb = blockIdx.x, col = threadIdx.x;
  __shared__ float al[4][256];
  for (int i = threadIdx.x; i < 4 * 256; i += 256)
    al[i >> 8][i & 255] = aw[(rb * 4 + (i >> 8)) * 256 + (i & 255)];
  __syncthreads();
  float acc[4] = {0, 0, 0, 0};
  #pragma unroll 8
  for (int kk = 0; kk < 256; kk++) {
    float wv = Wo[kk * 256 + col];
    #pragma unroll
    for (int r = 0; r < 4; r++) acc[r] += al[r][kk] * wv;
  }
  #pragma unroll
  for (int r = 0; r < 4; r++) {
    int row = rb * 4 + r;
    x2[row * 256 + col] = x[row * 256 + col] + acc[r] + bo[col];
  }
}

// hid = gelu(y2 @ ffn_W1 + b1). grid (256, 4)
__global__ __launch_bounds__(256) void ffn1_kernel(
    const float* __restrict__ y2, const float* __restrict__ W1,
    const float* __restrict__ b1, float* __restrict__ hid)
{
  int rb = blockIdx.x, col = blockIdx.y * 256 + threadIdx.x;
  __shared__ float yl[8][256];
  for (int i = threadIdx.x; i < 8 * 256; i += 256)
    yl[i >> 8][i & 255] = y2[(rb * 8 + (i >> 8)) * 256 + (i & 255)];
  __syncthreads();
  float acc[8] = {0, 0, 0, 0, 0, 0, 0, 0};
  #pragma unroll 8
  for (int kk = 0; kk < 256; kk++) {
    float wv = W1[kk * FF + col];
    #pragma unroll
    for (int r = 0; r < 8; r++) acc[r] += yl[r][kk] * wv;
  }
  #pragma unroll
  for (int r = 0; r < 8; r++)
    hid[(size_t)(rb * 8 + r) * FF + col] = gelu_f(acc[r] + b1[col]);
}

// ffn2 partial: K-split x4. grid (256, 4). partial[kc] = hid_chunk @ W2_chunk
__global__ __launch_bounds__(256) void ffn2_partial_kernel(
    const float* __restrict__ hid, const float* __restrict__ W2,
    float* __restrict__ p0, float* __restrict__ p1,
    float* __restrict__ p2, float* __restrict__ p3)
{
  int rb = blockIdx.x, kc = blockIdx.y, col = threadIdx.x;
  float* pout = (kc == 0) ? p0 : ((kc == 1) ? p1 : ((kc == 2) ? p2 : p3));
  __shared__ float hl[8][256];  // 8 KB
  for (int i = threadIdx.x; i < 2048; i += 256)
    hl[i >> 8][i & 255] = hid[(size_t)(rb * 8 + (i >> 8)) * FF + kc * 256 + (i & 255)];
  __syncthreads();
  float acc[8] = {0, 0, 0, 0, 0, 0, 0, 0};
  #pragma unroll 8
  for (int kk = 0; kk < 256; kk++) {
    float wv = W2[(kc * 256 + kk) * 256 + col];
    #pragma unroll
    for (int r = 0; r < 8; r++) acc[r] += hl[r][kk] * wv;
  }
  #pragma unroll
  for (int r = 0; r < 8; r++)
    pout[(size_t)(rb * 8 + r) * 256 + col] = acc[r];
}

// ffn2 finalize: psu = x2 + sum(partials) + b2 ; psub bf16. grid 2048
__global__ __launch_bounds__(256) void ffn2_fin_kernel(
    const float* __restrict__ x2,
    const float* __restrict__ p0, const float* __restrict__ p1,
    const float* __restrict__ p2, const float* __restrict__ p3,
    const float* __restrict__ b2,
    float* __restrict__ psu_out, unsigned short* __restrict__ psub)
{
  int row = blockIdx.x, col = threadIdx.x;
  size_t i = (size_t)row * 256 + col;
  float tv = x2[i] + ((p0[i] + p1[i]) + (p2[i] + p3[i])) + b2[col];
  psu_out[i] = tv;
  psub[i] = f2bf(tv);
}

// Pre-pack mlp weights to bf16 in MFMA-fragment order.
__global__ __launch_bounds__(256) void wprep_kernel(
    const float* __restrict__ mW1, const float* __restrict__ mW2,
    unsigned short* __restrict__ W1f, unsigned short* __restrict__ W2f)
{
  int i = blockIdx.x * 256 + threadIdx.x;
  if (i < 131072) {
    int tile = i >> 9, idx = i & 511;
    int lane = idx >> 3, j = idx & 7;
    int c = tile >> 4, kc = tile & 15;
    int k = kc * 32 + (lane >> 4) * 8 + j;
    int col = c * 16 + (lane & 15);
    W1f[i] = f2bf(mW1[k * 256 + col]);
  } else {
    int i2 = i - 131072;
    int tile = i2 >> 9, idx = i2 & 511;
    int lane = idx >> 3, j = idx & 7;
    int c = tile >> 3, kc = tile & 7;
    int k = kc * 32 + (lane >> 4) * 8 + j;
    int col = c * 16 + (lane & 15);
    W2f[i2] = f2bf(mW2[k * 256 + col]);
  }
}

// ---------------- Phase C: fused node MLP (bf16 MFMA) ----------------
// 32-row tiles, grid 4096, LDS 16.9KB -> 5 blocks/CU (launch_bounds 256,5).
#define AP2 264  // A/Hid row stride (bf16): 256 + 8 pad
#define CP2 260  // C row stride (f32): 256 + 4 pad (16-row pass)
__global__ __launch_bounds__(256, 5) void node_mlp_kernel(
    const float* __restrict__ H, const int* __restrict__ pids,
    const unsigned short* __restrict__ psub,
    const unsigned short* __restrict__ W1f, const unsigned short* __restrict__ W2f,
    const float* __restrict__ b1, const float* __restrict__ b2,
    float* __restrict__ out)
{
  __shared__ __align__(16) unsigned char smem[32 * AP2 * 2];  // 16896 B
  __shared__ int pidl[32];
  unsigned short* Ah = (unsigned short*)smem;   // A half / Hid (bf16), 32 rows
  float* Cl = (float*)smem;                     // C (f32), 16-row passes
  int tid = threadIdx.x;
  int lane = tid & 63, w = tid >> 6;
  int ln15 = lane & 15, hi = lane >> 4;
  int base = blockIdx.x * 32;

  f32x4 acc[2][4];
  #pragma unroll
  for (int a = 0; a < 2; a++)
    #pragma unroll
    for (int c = 0; c < 4; c++) acc[a][c] = (f32x4){0.f, 0.f, 0.f, 0.f};

  // ---- stage A half 1: H part (cols 0..255), fp32 -> bf16 ----
  if (tid < 32) pidl[tid] = pids[base + tid];
  for (int i = tid; i < 32 * 64; i += 256) {
    int r = i >> 6, c4 = i & 63;
    float4 f = *(const float4*)(H + ((size_t)(base + r)) * 256 + c4 * 4);
    unsigned int lo = (unsigned int)f2bf(f.x) | ((unsigned int)f2bf(f.y) << 16);
    unsigned int hi2 = (unsigned int)f2bf(f.z) | ((unsigned int)f2bf(f.w) << 16);
    u32x2 val = {lo, hi2};
    *((u32x2*)&Ah[r * AP2 + c4 * 4]) = val;
  }
  __syncthreads();

  const unsigned short* Wl1 = W1f + (size_t)lane * 8;
  // ---- GEMM1 kc 0..7 (K 0..255) ----
  {
    short8 bcur[4];
    #pragma unroll
    for (int ct = 0; ct < 4; ct++)
      bcur[ct] = *(const short8*)(Wl1 + ((w * 4 + ct) * 16 + 0) * 512);
    #pragma unroll
    for (int kc = 0; kc < 8; kc++) {
      short8 a[2], bnext[4];
      #pragma unroll
      for (int rt = 0; rt < 2; rt++)
        a[rt] = *(const short8*)(&Ah[(rt * 16 + ln15) * AP2 + kc * 32 + hi * 8]);
      #pragma unroll
      for (int ct = 0; ct < 4; ct++)
        bnext[ct] = *(const short8*)(Wl1 + ((w * 4 + ct) * 16 + kc + 1) * 512);
      __builtin_amdgcn_s_setprio(1);
      #pragma unroll
      for (int rt = 0; rt < 2; rt++)
        #pragma unroll
        for (int ct = 0; ct < 4; ct++)
          acc[rt][ct] = __builtin_amdgcn_mfma_f32_16x16x32_bf16(a[rt], bcur[ct], acc[rt][ct], 0, 0, 0);
      __builtin_amdgcn_s_setprio(0);
      #pragma unroll
      for (int ct = 0; ct < 4; ct++) bcur[ct] = bnext[ct];
    }
  }
  __syncthreads();

  // ---- stage A half 2: psu gather (cols 256..511) ----
  for (int i = tid; i < 32 * 32; i += 256) {
    int r = i >> 5, ch = i & 31;
    int node = base + r;
    int ss = node >> 15;
    int pid = pidl[r];
    *((u32x4*)&Ah[r * AP2 + ch * 8]) =
        *(const u32x4*)(psub + ((size_t)(ss * KSEG + pid)) * 256 + ch * 8);
  }
  __syncthreads();

  // ---- GEMM1 kc 8..15 (K 256..511) ----
  {
    short8 bcur[4];
    #pragma unroll
    for (int ct = 0; ct < 4; ct++)
      bcur[ct] = *(const short8*)(Wl1 + ((w * 4 + ct) * 16 + 8) * 512);
    #pragma unroll
    for (int kc = 8; kc < 16; kc++) {
      short8 a[2], bnext[4];
      #pragma unroll
      for (int rt = 0; rt < 2; rt++)
        a[rt] = *(const short8*)(&Ah[(rt * 16 + ln15) * AP2 + (kc - 8) * 32 + hi * 8]);
      if (kc < 15) {
        #pragma unroll
        for (int ct = 0; ct < 4; ct++)
          bnext[ct] = *(const short8*)(Wl1 + ((w * 4 + ct) * 16 + kc + 1) * 512);
      }
      __builtin_amdgcn_s_setprio(1);
      #pragma unroll
      for (int rt = 0; rt < 2; rt++)
        #pragma unroll
        for (int ct = 0; ct < 4; ct++)
          acc[rt][ct] = __builtin_amdgcn_mfma_f32_16x16x32_bf16(a[rt], bcur[ct], acc[rt][ct], 0, 0, 0);
      __builtin_amdgcn_s_setprio(0);
      if (kc < 15) {
        #pragma unroll
        for (int ct = 0; ct < 4; ct++) bcur[ct] = bnext[ct];
      }
    }
  }
  __syncthreads();

  // ---- epilogue 1: bias + gelu -> Hid (aliased over Ah) ----
  #pragma unroll
  for (int rt = 0; rt < 2; rt++) {
    #pragma unroll
    for (int ct = 0; ct < 4; ct++) {
      int col = w * 64 + ct * 16 + ln15;
      float bb = b1[col];
      #pragma unroll
      for (int r = 0; r < 4; r++) {
        int row = rt * 16 + hi * 4 + r;
        Ah[row * AP2 + col] = f2bf(gelu_f(acc[rt][ct][r] + bb));
      }
      acc[rt][ct] = (f32x4){0.f, 0.f, 0.f, 0.f};
    }
  }
  __syncthreads();

  // ---- GEMM2: [32x256] @ [256x256] ----
  {
    const unsigned short* Wl2 = W2f + (size_t)lane * 8;
    short8 bcur[4];
    #pragma unroll
    for (int ct = 0; ct < 4; ct++)
      bcur[ct] = *(const short8*)(Wl2 + ((w * 4 + ct) * 8 + 0) * 512);
    #pragma unroll
    for (int kc = 0; kc < 8; kc++) {
      short8 a[2], bnext[4];
      #pragma unroll
      for (int rt = 0; rt < 2; rt++)
        a[rt] = *(const short8*)(&Ah[(rt * 16 + ln15) * AP2 + kc * 32 + hi * 8]);
      if (kc < 7) {
        #pragma unroll
        for (int ct = 0; ct < 4; ct++)
          bnext[ct] = *(const short8*)(Wl2 + ((w * 4 + ct) * 8 + kc + 1) * 512);
      }
      __builtin_amdgcn_s_setprio(1);
      #pragma unroll
      for (int rt = 0; rt < 2; rt++)
        #pragma unroll
        for (int ct = 0; ct < 4; ct++)
          acc[rt][ct] = __builtin_amdgcn_mfma_f32_16x16x32_bf16(a[rt], bcur[ct], acc[rt][ct], 0, 0, 0);
      __builtin_amdgcn_s_setprio(0);
      if (kc < 7) {
        #pragma unroll
        for (int ct = 0; ct < 4; ct++) bcur[ct] = bnext[ct];
      }
    }
  }

  // ---- final epilogue: two 16-row passes through LDS ----
  #pragma unroll
  for (int rh = 0; rh < 2; rh++) {
    __syncthreads();
    #pragma unroll
    for (int ct = 0; ct < 4; ct++) {
      int col = w * 64 + ct * 16 + ln15;
      float bb = b2[col];
      #pragma unroll
      for (int r = 0; r < 4; r++)
        Cl[(hi * 4 + r) * CP2 + col] = acc[rh][ct][r] + bb;
    }
    __syncthreads();
    for (int i = tid; i < 16 * 64; i += 256) {
      int r = i >> 6, c4 = i & 63;
      size_t gidx = ((size_t)(base + rh * 16 + r)) * 256 + c4 * 4;
      float4 h4 = *(const float4*)(H + gidx);
      float4 cv = *(const float4*)&Cl[r * CP2 + c4 * 4];
      float4 o4 = {h4.x + cv.x, h4.y + cv.y, h4.z + cv.z, h4.w + cv.w};
      *(float4*)(out + gidx) = o4;
    }
  }
}

extern "C" void kernel_launch(void* const* d_in, const int* in_sizes, int n_in,
                              void* d_out, int out_size, void* d_ws, size_t ws_size,
                              hipStream_t stream) {
  (void)in_sizes; (void)n_in; (void)out_size; (void)ws_size;
  const float* H    = (const float*)d_in[0];
  const int*   pids = (const int*)d_in[1];
  const float* ln1g = (const float*)d_in[2];
  const float* ln1b = (const float*)d_in[3];
  const float* Wq   = (const float*)d_in[4];
  const float* bq   = (const float*)d_in[5];
  const float* Wk   = (const float*)d_in[6];
  const float* bk   = (const float*)d_in[7];
  const float* Wv   = (const float*)d_in[8];
  const float* bv   = (const float*)d_in[9];
  const float* Wo   = (const float*)d_in[10];
  const float* bo   = (const float*)d_in[11];
  const float* ln2g = (const float*)d_in[12];
  const float* ln2b = (const float*)d_in[13];
  const float* fW1  = (const float*)d_in[14];
  const float* fb1  = (const float*)d_in[15];
  const float* fW2  = (const float*)d_in[16];
  const float* fb2  = (const float*)d_in[17];
  const float* mW1  = (const float*)d_in[18];
  const float* mb1  = (const float*)d_in[19];
  const float* mW2  = (const float*)d_in[20];
  const float* mb2  = (const float*)d_in[21];
  float* out = (float*)d_out;
  float* ws = (float*)d_ws;

  int*   histc   = (int*)ws;                         // 32768 ints
  int*   segstart= (int*)(ws + 32768);               // 2048
  int*   cnti    = (int*)(ws + 34816);               // 2048
  int*   order   = (int*)(ws + 36864);               // 131072
  float* counts  = ws + 524288;                      // 2048
  float* xw      = ws + 526336;                      // 524288
  float* yw      = ws + 1050624;                     // 524288
  float* qw      = ws + 1574912;                     // 524288  (later: ffn2 partial0)
  float* kw      = ws + 2099200;                     // 524288  (later: partial1)
  float* vw      = ws + 2623488;                     // 524288  (later: partial2)
  float* kvb     = ws + 3147776;                     // 65536
  float* ksb     = ws + 3213312;                     // 1024
  float* aw      = ws + 3214336;                     // 524288  (later: partial3)
  float* x2w     = ws + 3738624;                     // 524288
  float* y2w     = ws + 4262912;                     // 524288
  float* hidw    = ws + 4787200;                     // 2097152
  unsigned short* psub = (unsigned short*)(ws + 6884352);  // 524288 bf16
  unsigned short* W1f  = (unsigned short*)(ws + 7146496);  // 131072 bf16
  unsigned short* W2f  = (unsigned short*)(ws + 7212032);  // 65536 bf16

  hipMemsetAsync(kvb, 0, (65536 + 1024) * sizeof(float), stream);

  wprep_kernel<<<768, 256, 0, stream>>>(mW1, mW2, W1f, W2f);
  hist_kernel<<<64, 256, 0, stream>>>(pids, histc);
  prefix_kernel<<<4, 256, 0, stream>>>(histc, segstart, cnti, counts);
  scatter_kernel<<<64, 256, 0, stream>>>(pids, histc, order);
  pool_gather<<<1024, 256, 0, stream>>>(H, order, segstart, cnti, xw);
  pool_ln_kernel<<<2048, 256, 0, stream>>>(xw, ln1g, ln1b, yw);
  qkv_kernel<<<dim3(512, 3), 256, 0, stream>>>(yw, counts, Wq, bq, Wk, bk, Wv, bv, qw, kw, vw);
  kv_kernel<<<128, 256, 0, stream>>>(kw, vw, kvb, ksb);
  attn_kernel<<<256, 256, 0, stream>>>(qw, kvb, ksb, aw);
  oproj_kernel<<<512, 256, 0, stream>>>(aw, xw, Wo, bo, x2w);
  ln_kernel<<<2048, 256, 0, stream>>>(x2w, y2w, ln2g, ln2b);
  ffn1_kernel<<<dim3(256, 4), 256, 0, stream>>>(y2w, fW1, fb1, hidw);
  ffn2_partial_kernel<<<dim3(256, 4), 256, 0, stream>>>(hidw, fW2, qw, kw, vw, aw);
  ffn2_fin_kernel<<<2048, 256, 0, stream>>>(x2w, qw, kw, vw, aw, fb2,
                                            out + (size_t)S * N * D, psub);
  node_mlp_kernel<<<4096, 256, 0, stream>>>(H, pids, psub, W1f, W2f, mb1, mb2, out);
}

// Round 7
// 237.786 us; speedup vs baseline: 1.9434x; 1.9434x over previous
//
#include <hip/hip_runtime.h>
#include <hip/hip_bf16.h>

#define S 4
#define N 32768
#define D 256
#define KSEG 512
#define NH 4
#define HD 64
#define FF 1024

typedef __attribute__((ext_vector_type(8))) short short8;
typedef __attribute__((ext_vector_type(4))) float f32x4;
typedef __attribute__((ext_vector_type(4))) unsigned int u32x4;
typedef __attribute__((ext_vector_type(2))) unsigned int u32x2;

__device__ __forceinline__ unsigned short f2bf(float f) {
  union { __hip_bfloat16 h; unsigned short u; } cv;
  cv.h = __float2bfloat16(f);
  return cv.u;
}

__device__ __forceinline__ float gelu_f(float x) {
  return 0.5f * x * (1.0f + erff(x * 0.70710678118654752440f));
}

__device__ __forceinline__ float wave_reduce_sum(float v) {
  #pragma unroll
  for (int o = 32; o > 0; o >>= 1) v += __shfl_xor(v, o, 64);
  return v;
}

// ---------------- Phase A: counting sort by patch id ----------------
__global__ __launch_bounds__(256) void hist_kernel(
    const int* __restrict__ pids, int* __restrict__ histc)
{
  __shared__ int h[KSEG];
  int b = blockIdx.x, t = threadIdx.x;
  int s = b >> 4, c = b & 15;
  for (int i = t; i < KSEG; i += 256) h[i] = 0;
  __syncthreads();
  const int* p = pids + s * N + c * 2048;
  for (int i = t; i < 2048; i += 256) atomicAdd(&h[p[i]], 1);
  __syncthreads();
  for (int i = t; i < KSEG; i += 256) histc[(s * 16 + c) * KSEG + i] = h[i];
}

__global__ __launch_bounds__(256) void prefix_kernel(
    int* __restrict__ histc, int* __restrict__ segstart,
    int* __restrict__ cnti, float* __restrict__ counts)
{
  __shared__ int h[16 * KSEG];   // 32 KB
  __shared__ int sc[KSEG];
  __shared__ int sa[KSEG], sb[KSEG];
  int s = blockIdx.x, t = threadIdx.x;
  for (int i = t; i < 16 * KSEG; i += 256) h[i] = histc[s * 16 * KSEG + i];
  __syncthreads();
  #pragma unroll
  for (int u = 0; u < 2; u++) {
    int bin = t + u * 256;
    int cc = 0;
    #pragma unroll
    for (int c = 0; c < 16; c++) cc += h[c * KSEG + bin];
    sc[bin] = cc;
    sa[bin] = cc;
  }
  __syncthreads();
  int* src = sa; int* dst = sb;
  for (int off = 1; off < KSEG; off <<= 1) {
    #pragma unroll
    for (int u = 0; u < 2; u++) {
      int bin = t + u * 256;
      int v = src[bin];
      if (bin >= off) v += src[bin - off];
      dst[bin] = v;
    }
    __syncthreads();
    int* tmp = src; src = dst; dst = tmp;
  }
  #pragma unroll
  for (int u = 0; u < 2; u++) {
    int bin = t + u * 256;
    int cc = sc[bin];
    int excl = src[bin] - cc;
    segstart[s * KSEG + bin] = excl;
    cnti[s * KSEG + bin] = cc;
    counts[s * KSEG + bin] = (float)cc;
    int run = excl;
    #pragma unroll
    for (int c = 0; c < 16; c++) {
      int v = h[c * KSEG + bin];
      h[c * KSEG + bin] = run;
      run += v;
    }
  }
  __syncthreads();
  for (int i = t; i < 16 * KSEG; i += 256) histc[s * 16 * KSEG + i] = h[i];
}

__global__ __launch_bounds__(256) void scatter_kernel(
    const int* __restrict__ pids, const int* __restrict__ histc,
    int* __restrict__ order)
{
  __shared__ int offs[KSEG];
  int b = blockIdx.x, t = threadIdx.x;
  int s = b >> 4, c = b & 15;
  for (int i = t; i < KSEG; i += 256) offs[i] = histc[(s * 16 + c) * KSEG + i];
  __syncthreads();
  const int* p = pids + s * N + c * 2048;
  for (int i = t; i < 2048; i += 256) {
    int pid = p[i];
    int pos = atomicAdd(&offs[pid], 1);
    order[s * N + pos] = s * N + c * 2048 + i;
  }
}

// gather-reduce: TWO waves per segment. grid 1024.
__global__ __launch_bounds__(256) void pool_gather(
    const float* __restrict__ H, const int* __restrict__ order,
    const int* __restrict__ segstart, const int* __restrict__ cnti,
    float* __restrict__ xw)
{
  __shared__ float pbuf[4][256];
  int tid = threadIdx.x;
  int w = tid >> 6, lane = tid & 63;
  int seg = blockIdx.x * 2 + (w >> 1);
  int half = w & 1;
  int s = seg >> 9;
  int st = segstart[seg], cn = cnti[seg];
  int en = st + cn;
  const int* ord = order + (size_t)s * N;
  int c4 = lane << 2;
  f32x4 a0 = {0,0,0,0}, a1 = {0,0,0,0}, a2 = {0,0,0,0}, a3 = {0,0,0,0};
  f32x4 a4 = {0,0,0,0}, a5 = {0,0,0,0}, a6 = {0,0,0,0}, a7 = {0,0,0,0};
  int i = st + half;
  for (; i + 14 < en; i += 16) {
    int r0 = ord[i + 0], r1 = ord[i + 2], r2 = ord[i + 4], r3 = ord[i + 6];
    int r4 = ord[i + 8], r5 = ord[i + 10], r6 = ord[i + 12], r7 = ord[i + 14];
    a0 += *(const f32x4*)(H + (size_t)r0 * 256 + c4);
    a1 += *(const f32x4*)(H + (size_t)r1 * 256 + c4);
    a2 += *(const f32x4*)(H + (size_t)r2 * 256 + c4);
    a3 += *(const f32x4*)(H + (size_t)r3 * 256 + c4);
    a4 += *(const f32x4*)(H + (size_t)r4 * 256 + c4);
    a5 += *(const f32x4*)(H + (size_t)r5 * 256 + c4);
    a6 += *(const f32x4*)(H + (size_t)r6 * 256 + c4);
    a7 += *(const f32x4*)(H + (size_t)r7 * 256 + c4);
  }
  for (; i < en; i += 2) {
    int r = ord[i];
    a0 += *(const f32x4*)(H + (size_t)r * 256 + c4);
  }
  f32x4 ssum = ((a0 + a1) + (a2 + a3)) + ((a4 + a5) + (a6 + a7));
  *(f32x4*)&pbuf[w][c4] = ssum;
  __syncthreads();
  if (half == 0) {
    f32x4 tot = *(f32x4*)&pbuf[w][c4];
    tot += *(f32x4*)&pbuf[w + 1][c4];
    float inv = 1.f / fmaxf((float)cn, 1.f);
    tot = tot * inv;
    *(f32x4*)(xw + (size_t)seg * 256 + c4) = tot;
  }
}

// y = LN(x). grid 2048 rows
__global__ __launch_bounds__(256) void pool_ln_kernel(
    const float* __restrict__ xw,
    const float* __restrict__ g, const float* __restrict__ b,
    float* __restrict__ yw)
{
  int row = blockIdx.x, t = threadIdx.x;
  float v = xw[row * 256 + t];
  float s1 = wave_reduce_sum(v);
  float s2 = wave_reduce_sum(v * v);
  __shared__ float a1[4], a2[4];
  int w = t >> 6;
  if ((t & 63) == 0) { a1[w] = s1; a2[w] = s2; }
  __syncthreads();
  float ts1 = a1[0] + a1[1] + a1[2] + a1[3];
  float ts2 = a2[0] + a2[1] + a2[2] + a2[3];
  float mu = ts1 * (1.f / 256.f);
  float var = ts2 * (1.f / 256.f) - mu * mu;
  yw[row * 256 + t] = (v - mu) * rsqrtf(var + 1e-5f) * g[t] + b[t];
}

__global__ __launch_bounds__(256) void ln_kernel(
    const float* __restrict__ in, float* __restrict__ outp,
    const float* __restrict__ g, const float* __restrict__ b)
{
  int row = blockIdx.x, t = threadIdx.x;
  float v = in[row * 256 + t];
  float s1 = wave_reduce_sum(v);
  float s2 = wave_reduce_sum(v * v);
  __shared__ float a1[4], a2[4];
  int w = t >> 6;
  if ((t & 63) == 0) { a1[w] = s1; a2[w] = s2; }
  __syncthreads();
  float ts1 = a1[0] + a1[1] + a1[2] + a1[3];
  float ts2 = a2[0] + a2[1] + a2[2] + a2[3];
  float mu = ts1 * (1.f / 256.f);
  float var = ts2 * (1.f / 256.f) - mu * mu;
  outp[row * 256 + t] = (v - mu) * rsqrtf(var + 1e-5f) * g[t] + b[t];
}

// ---------------- weight pre-pack: all 8 matrices into fragment order ----
// Fragment layout (proven in node_mlp): region of 16c x KC tiles, tile=c*KC+kc,
// 512 shorts/tile; short idx = lane*8+j; k = kc*32+(lane>>4)*8+j,
// col = colbase + c*16 + (lane&15); src row-major [K x ld].
// Regions (fragment-8 units, 122880 total):
//  [0,8192)x4: Wq,Wk,Wv,Wo K=256 ld=256  -> out 0,65536,131072,196608
//  [32768,65536): fW1 4 col-chunks K=256 ld=1024 -> 262144+cc*65536
//  [65536,98304): fW2 K=1024 ld=256 -> 524288
//  [98304,114688): mW1 K=512 ld=256 -> 786432
//  [114688,122880): mW2 K=256 ld=256 -> 917504
__global__ __launch_bounds__(256) void wprep2_kernel(
    const float* __restrict__ Wq, const float* __restrict__ Wk,
    const float* __restrict__ Wv, const float* __restrict__ Wo,
    const float* __restrict__ fW1, const float* __restrict__ fW2,
    const float* __restrict__ mW1, const float* __restrict__ mW2,
    unsigned short* __restrict__ Wpack)
{
  int fi = blockIdx.x * 256 + threadIdx.x;   // 0..122879
  const float* src; int ld, colbase, kcbits; size_t outb; int rfi;
  if (fi < 32768) {
    int m = fi >> 13; rfi = fi & 8191;
    src = (m == 0) ? Wq : ((m == 1) ? Wk : ((m == 2) ? Wv : Wo));
    ld = 256; colbase = 0; kcbits = 3; outb = (size_t)m * 65536;
  } else if (fi < 65536) {
    rfi = fi - 32768; int cc = rfi >> 13; rfi &= 8191;
    src = fW1; ld = 1024; colbase = cc * 256; kcbits = 3;
    outb = 262144 + (size_t)cc * 65536;
  } else if (fi < 98304) {
    rfi = fi - 65536; src = fW2; ld = 256; colbase = 0; kcbits = 5; outb = 524288;
  } else if (fi < 114688) {
    rfi = fi - 98304; src = mW1; ld = 256; colbase = 0; kcbits = 4; outb = 786432;
  } else {
    rfi = fi - 114688; src = mW2; ld = 256; colbase = 0; kcbits = 3; outb = 917504;
  }
  int tile = rfi >> 6, lane = rfi & 63;
  int c = tile >> kcbits, kc = tile & ((1 << kcbits) - 1);
  int k0 = kc * 32 + (lane >> 4) * 8;
  int col = colbase + c * 16 + (lane & 15);
  unsigned int p[4];
  #pragma unroll
  for (int jj = 0; jj < 4; jj++) {
    unsigned int lo = f2bf(src[(size_t)(k0 + 2 * jj) * ld + col]);
    unsigned int hi = f2bf(src[(size_t)(k0 + 2 * jj + 1) * ld + col]);
    p[jj] = lo | (hi << 16);
  }
  u32x4 v = {p[0], p[1], p[2], p[3]};
  *(u32x4*)&Wpack[outb + (size_t)rfi * 8] = v;
}

// ---------------- MFMA patch-GEMM template pieces (16 rows x 256 cols) ----
#define AP3 264  // A row stride (bf16): 256 + 8 pad
#define CP3 260  // C row stride (f32): 256 + 4 pad

// QKV: grid (128, 3). epilogue: phi (m<=1), mask (m>=1).
__global__ __launch_bounds__(256, 4) void qkv_mfma(
    const float* __restrict__ y, const float* __restrict__ counts,
    const unsigned short* __restrict__ Wpack,
    const float* __restrict__ bq, const float* __restrict__ bk,
    const float* __restrict__ bv,
    float* __restrict__ qo, float* __restrict__ ko, float* __restrict__ vo)
{
  __shared__ __align__(16) unsigned char smem[16 * CP3 * 4];  // 16640 B
  unsigned short* Ah = (unsigned short*)smem;
  float* Cl = (float*)smem;
  int m = blockIdx.y;
  const unsigned short* Wf = Wpack + (size_t)m * 65536;
  const float* bias = (m == 0) ? bq : ((m == 1) ? bk : bv);
  float* outp = (m == 0) ? qo : ((m == 1) ? ko : vo);
  int tid = threadIdx.x, lane = tid & 63, w = tid >> 6;
  int ln15 = lane & 15, hi = lane >> 4;
  int base = blockIdx.x * 16;

  for (int i = tid; i < 16 * 64; i += 256) {
    int r = i >> 6, c4 = i & 63;
    float4 f = *(const float4*)(y + ((size_t)(base + r)) * 256 + c4 * 4);
    unsigned int lo = (unsigned int)f2bf(f.x) | ((unsigned int)f2bf(f.y) << 16);
    unsigned int h2 = (unsigned int)f2bf(f.z) | ((unsigned int)f2bf(f.w) << 16);
    u32x2 val = {lo, h2};
    *((u32x2*)&Ah[r * AP3 + c4 * 4]) = val;
  }
  __syncthreads();

  f32x4 acc[4];
  #pragma unroll
  for (int c = 0; c < 4; c++) acc[c] = (f32x4){0.f, 0.f, 0.f, 0.f};
  const unsigned short* Wl = Wf + (size_t)lane * 8;
  short8 bcur[4];
  #pragma unroll
  for (int ct = 0; ct < 4; ct++)
    bcur[ct] = *(const short8*)(Wl + ((w * 4 + ct) * 8 + 0) * 512);
  #pragma unroll
  for (int kc = 0; kc < 8; kc++) {
    short8 a = *(const short8*)(&Ah[ln15 * AP3 + kc * 32 + hi * 8]);
    short8 bnext[4];
    if (kc < 7) {
      #pragma unroll
      for (int ct = 0; ct < 4; ct++)
        bnext[ct] = *(const short8*)(Wl + ((w * 4 + ct) * 8 + kc + 1) * 512);
    }
    #pragma unroll
    for (int ct = 0; ct < 4; ct++)
      acc[ct] = __builtin_amdgcn_mfma_f32_16x16x32_bf16(a, bcur[ct], acc[ct], 0, 0, 0);
    if (kc < 7) {
      #pragma unroll
      for (int ct = 0; ct < 4; ct++) bcur[ct] = bnext[ct];
    }
  }
  __syncthreads();  // A reads done; reuse smem as Cl

  float mk[4];
  #pragma unroll
  for (int r = 0; r < 4; r++)
    mk[r] = (counts[base + hi * 4 + r] > 0.f) ? 1.f : 0.f;
  #pragma unroll
  for (int ct = 0; ct < 4; ct++) {
    int col = w * 64 + ct * 16 + ln15;
    float bb = bias[col];
    #pragma unroll
    for (int r = 0; r < 4; r++) {
      float tv = acc[ct][r] + bb;
      if (m <= 1) tv = (tv > 0.f) ? (tv + 1.f) : expf(tv);
      if (m >= 1) tv *= mk[r];
      Cl[(hi * 4 + r) * CP3 + col] = tv;
    }
  }
  __syncthreads();
  for (int i = tid; i < 16 * 64; i += 256) {
    int r = i >> 6, c4 = i & 63;
    *(float4*)(outp + ((size_t)(base + r)) * 256 + c4 * 4) =
        *(const float4*)&Cl[r * CP3 + c4 * 4];
  }
}

// oproj: x2 = x + a@Wo + bo. grid 128.
__global__ __launch_bounds__(256, 4) void oproj_mfma(
    const float* __restrict__ aw, const float* __restrict__ xw,
    const unsigned short* __restrict__ Wpack, const float* __restrict__ bo,
    float* __restrict__ x2)
{
  __shared__ __align__(16) unsigned char smem[16 * CP3 * 4];
  unsigned short* Ah = (unsigned short*)smem;
  float* Cl = (float*)smem;
  const unsigned short* Wf = Wpack + 196608;
  int tid = threadIdx.x, lane = tid & 63, w = tid >> 6;
  int ln15 = lane & 15, hi = lane >> 4;
  int base = blockIdx.x * 16;

  for (int i = tid; i < 16 * 64; i += 256) {
    int r = i >> 6, c4 = i & 63;
    float4 f = *(const float4*)(aw + ((size_t)(base + r)) * 256 + c4 * 4);
    unsigned int lo = (unsigned int)f2bf(f.x) | ((unsigned int)f2bf(f.y) << 16);
    unsigned int h2 = (unsigned int)f2bf(f.z) | ((unsigned int)f2bf(f.w) << 16);
    u32x2 val = {lo, h2};
    *((u32x2*)&Ah[r * AP3 + c4 * 4]) = val;
  }
  __syncthreads();

  f32x4 acc[4];
  #pragma unroll
  for (int c = 0; c < 4; c++) acc[c] = (f32x4){0.f, 0.f, 0.f, 0.f};
  const unsigned short* Wl = Wf + (size_t)lane * 8;
  short8 bcur[4];
  #pragma unroll
  for (int ct = 0; ct < 4; ct++)
    bcur[ct] = *(const short8*)(Wl + ((w * 4 + ct) * 8 + 0) * 512);
  #pragma unroll
  for (int kc = 0; kc < 8; kc++) {
    short8 a = *(const short8*)(&Ah[ln15 * AP3 + kc * 32 + hi * 8]);
    short8 bnext[4];
    if (kc < 7) {
      #pragma unroll
      for (int ct = 0; ct < 4; ct++)
        bnext[ct] = *(const short8*)(Wl + ((w * 4 + ct) * 8 + kc + 1) * 512);
    }
    #pragma unroll
    for (int ct = 0; ct < 4; ct++)
      acc[ct] = __builtin_amdgcn_mfma_f32_16x16x32_bf16(a, bcur[ct], acc[ct], 0, 0, 0);
    if (kc < 7) {
      #pragma unroll
      for (int ct = 0; ct < 4; ct++) bcur[ct] = bnext[ct];
    }
  }
  __syncthreads();

  #pragma unroll
  for (int ct = 0; ct < 4; ct++) {
    int col = w * 64 + ct * 16 + ln15;
    float bb = bo[col];
    #pragma unroll
    for (int r = 0; r < 4; r++)
      Cl[(hi * 4 + r) * CP3 + col] = acc[ct][r] + bb;
  }
  __syncthreads();
  for (int i = tid; i < 16 * 64; i += 256) {
    int r = i >> 6, c4 = i & 63;
    size_t gidx = ((size_t)(base + r)) * 256 + c4 * 4;
    float4 xv = *(const float4*)(xw + gidx);
    float4 cv = *(const float4*)&Cl[r * CP3 + c4 * 4];
    float4 o = {xv.x + cv.x, xv.y + cv.y, xv.z + cv.z, xv.w + cv.w};
    *(float4*)(x2 + gidx) = o;
  }
}

// ffn1: hidb = bf16(gelu(y2 @ fW1 + b1)). grid (128, 4 col-chunks).
__global__ __launch_bounds__(256, 4) void ffn1_mfma(
    const float* __restrict__ y2, const unsigned short* __restrict__ Wpack,
    const float* __restrict__ b1, unsigned short* __restrict__ hidb)
{
  __shared__ __align__(16) unsigned char smem[16 * CP3 * 4];
  unsigned short* Ah = (unsigned short*)smem;
  int cc = blockIdx.y;
  const unsigned short* Wf = Wpack + 262144 + (size_t)cc * 65536;
  int tid = threadIdx.x, lane = tid & 63, w = tid >> 6;
  int ln15 = lane & 15, hi = lane >> 4;
  int base = blockIdx.x * 16;

  for (int i = tid; i < 16 * 64; i += 256) {
    int r = i >> 6, c4 = i & 63;
    float4 f = *(const float4*)(y2 + ((size_t)(base + r)) * 256 + c4 * 4);
    unsigned int lo = (unsigned int)f2bf(f.x) | ((unsigned int)f2bf(f.y) << 16);
    unsigned int h2 = (unsigned int)f2bf(f.z) | ((unsigned int)f2bf(f.w) << 16);
    u32x2 val = {lo, h2};
    *((u32x2*)&Ah[r * AP3 + c4 * 4]) = val;
  }
  __syncthreads();

  f32x4 acc[4];
  #pragma unroll
  for (int c = 0; c < 4; c++) acc[c] = (f32x4){0.f, 0.f, 0.f, 0.f};
  const unsigned short* Wl = Wf + (size_t)lane * 8;
  short8 bcur[4];
  #pragma unroll
  for (int ct = 0; ct < 4; ct++)
    bcur[ct] = *(const short8*)(Wl + ((w * 4 + ct) * 8 + 0) * 512);
  #pragma unroll
  for (int kc = 0; kc < 8; kc++) {
    short8 a = *(const short8*)(&Ah[ln15 * AP3 + kc * 32 + hi * 8]);
    short8 bnext[4];
    if (kc < 7) {
      #pragma unroll
      for (int ct = 0; ct < 4; ct++)
        bnext[ct] = *(const short8*)(Wl + ((w * 4 + ct) * 8 + kc + 1) * 512);
    }
    #pragma unroll
    for (int ct = 0; ct < 4; ct++)
      acc[ct] = __builtin_amdgcn_mfma_f32_16x16x32_bf16(a, bcur[ct], acc[ct], 0, 0, 0);
    if (kc < 7) {
      #pragma unroll
      for (int ct = 0; ct < 4; ct++) bcur[ct] = bnext[ct];
    }
  }
  __syncthreads();

  // epilogue: gelu -> LDS bf16 [16][256] -> coalesced global
  #pragma unroll
  for (int ct = 0; ct < 4; ct++) {
    int col = w * 64 + ct * 16 + ln15;
    float bb = b1[cc * 256 + col];
    #pragma unroll
    for (int r = 0; r < 4; r++)
      Ah[(hi * 4 + r) * 256 + col] = f2bf(gelu_f(acc[ct][r] + bb));
  }
  __syncthreads();
  for (int i = tid; i < 16 * 32; i += 256) {
    int r = i >> 5, c8 = i & 31;
    *(u32x4*)(hidb + ((size_t)(base + r)) * FF + cc * 256 + c8 * 8) =
        *(const u32x4*)&Ah[r * 256 + c8 * 8];
  }
}

// ffn2: psu = x2 + hidb @ fW2 + b2 (fp32 out + bf16 psub). grid 128. K=1024.
__global__ __launch_bounds__(256, 4) void ffn2_mfma(
    const unsigned short* __restrict__ hidb, const float* __restrict__ x2,
    const unsigned short* __restrict__ Wpack, const float* __restrict__ b2,
    float* __restrict__ psu_out, unsigned short* __restrict__ psub)
{
  __shared__ __align__(16) unsigned char smem[16 * CP3 * 4];
  unsigned short* Ah = (unsigned short*)smem;
  float* Cl = (float*)smem;
  const unsigned short* Wf = Wpack + 524288;
  int tid = threadIdx.x, lane = tid & 63, w = tid >> 6;
  int ln15 = lane & 15, hi = lane >> 4;
  int base = blockIdx.x * 16;

  f32x4 acc[4];
  #pragma unroll
  for (int c = 0; c < 4; c++) acc[c] = (f32x4){0.f, 0.f, 0.f, 0.f};
  const unsigned short* Wl = Wf + (size_t)lane * 8;

  for (int ch = 0; ch < 4; ch++) {
    __syncthreads();  // prior chunk's A reads done
    for (int i = tid; i < 16 * 32; i += 256) {
      int r = i >> 5, c8 = i & 31;
      *((u32x4*)&Ah[r * AP3 + c8 * 8]) =
          *(const u32x4*)(hidb + ((size_t)(base + r)) * FF + ch * 256 + c8 * 8);
    }
    __syncthreads();
    short8 bcur[4];
    #pragma unroll
    for (int ct = 0; ct < 4; ct++)
      bcur[ct] = *(const short8*)(Wl + ((w * 4 + ct) * 32 + ch * 8 + 0) * 512);
    #pragma unroll
    for (int kc = 0; kc < 8; kc++) {
      short8 a = *(const short8*)(&Ah[ln15 * AP3 + kc * 32 + hi * 8]);
      short8 bnext[4];
      if (kc < 7) {
        #pragma unroll
        for (int ct = 0; ct < 4; ct++)
          bnext[ct] = *(const short8*)(Wl + ((w * 4 + ct) * 32 + ch * 8 + kc + 1) * 512);
      }
      #pragma unroll
      for (int ct = 0; ct < 4; ct++)
        acc[ct] = __builtin_amdgcn_mfma_f32_16x16x32_bf16(a, bcur[ct], acc[ct], 0, 0, 0);
      if (kc < 7) {
        #pragma unroll
        for (int ct = 0; ct < 4; ct++) bcur[ct] = bnext[ct];
      }
    }
  }
  __syncthreads();

  #pragma unroll
  for (int ct = 0; ct < 4; ct++) {
    int col = w * 64 + ct * 16 + ln15;
    float bb = b2[col];
    #pragma unroll
    for (int r = 0; r < 4; r++)
      Cl[(hi * 4 + r) * CP3 + col] = acc[ct][r] + bb;
  }
  __syncthreads();
  for (int i = tid; i < 16 * 64; i += 256) {
    int r = i >> 6, c4 = i & 63;
    size_t gidx = ((size_t)(base + r)) * 256 + c4 * 4;
    float4 xv = *(const float4*)(x2 + gidx);
    float4 cv = *(const float4*)&Cl[r * CP3 + c4 * 4];
    float4 o = {xv.x + cv.x, xv.y + cv.y, xv.z + cv.z, xv.w + cv.w};
    *(float4*)(psu_out + gidx) = o;
    unsigned int lo = (unsigned int)f2bf(o.x) | ((unsigned int)f2bf(o.y) << 16);
    unsigned int h2 = (unsigned int)f2bf(o.z) | ((unsigned int)f2bf(o.w) << 16);
    u32x2 pb = {lo, h2};
    *(u32x2*)(psub + gidx) = pb;
  }
}

// kv[s,h,d,e] = sum_k k*v ; ksum. grid 128
__global__ __launch_bounds__(256) void kv_kernel(
    const float* __restrict__ kw, const float* __restrict__ vw,
    float* __restrict__ kvb, float* __restrict__ ksb)
{
  int b = blockIdx.x, t = threadIdx.x;
  int s = b / (NH * 8), h = (b / 8) % NH, ck = b & 7;
  __shared__ float kl[64 * 64];
  __shared__ float vl[64 * 64];
  for (int i = t; i < 4096; i += 256) {
    int kk = i >> 6, d = i & 63;
    size_t rowb = ((size_t)(s * KSEG + ck * 64 + kk) * NH + h) * HD + d;
    kl[i] = kw[rowb];
    vl[i] = vw[rowb];
  }
  __syncthreads();
  int d = t & 63, eb = (t >> 6) * 16;
  f32x4 a4[4];
  #pragma unroll
  for (int j = 0; j < 4; j++) a4[j] = (f32x4){0.f, 0.f, 0.f, 0.f};
  float acck = 0.f;
  #pragma unroll 4
  for (int kk = 0; kk < 64; kk++) {
    float kd = kl[kk * 64 + d];
    acck += kd;
    #pragma unroll
    for (int j = 0; j < 4; j++) {
      f32x4 vv = *(const f32x4*)&vl[kk * 64 + eb + j * 4];
      a4[j] += kd * vv;
    }
  }
  #pragma unroll
  for (int j = 0; j < 4; j++)
    #pragma unroll
    for (int e = 0; e < 4; e++)
      atomicAdd(&kvb[(((size_t)(s * NH + h)) * HD + d) * HD + eb + j * 4 + e], a4[j][e]);
  if (t < 64) atomicAdd(&ksb[(s * NH + h) * HD + t], acck);
}

// a = num/den per row. grid 256 blocks
__global__ __launch_bounds__(256) void attn_kernel(
    const float* __restrict__ qw, const float* __restrict__ kvb,
    const float* __restrict__ ksb, float* __restrict__ aw)
{
  __shared__ float kvl[64 * 64];
  __shared__ float ksl[64];
  __shared__ float ql[32 * 64];
  int t = threadIdx.x, b = blockIdx.x;
  int sh = b >> 4, rb = b & 15;
  int s = sh >> 2, h = sh & 3;
  for (int i = t; i < 4096; i += 256) kvl[i] = kvb[sh * 4096 + i];
  if (t < 64) ksl[t] = ksb[sh * 64 + t];
  for (int i = t; i < 2048; i += 256) {
    int r = i >> 6, d = i & 63;
    ql[i] = qw[((size_t)(s * KSEG + rb * 32 + r)) * 256 + h * 64 + d];
  }
  __syncthreads();
  int e = t & 63, rg = t >> 6;
  float num[8], den[8];
  #pragma unroll
  for (int r = 0; r < 8; r++) { num[r] = 0.f; den[r] = 0.f; }
  #pragma unroll 4
  for (int d4 = 0; d4 < 64; d4 += 4) {
    float4 ks4 = *(const float4*)&ksl[d4];
    float kv0 = kvl[(d4 + 0) * 64 + e];
    float kv1 = kvl[(d4 + 1) * 64 + e];
    float kv2 = kvl[(d4 + 2) * 64 + e];
    float kv3 = kvl[(d4 + 3) * 64 + e];
    #pragma unroll
    for (int r = 0; r < 8; r++) {
      float4 q4 = *(const float4*)&ql[(rg * 8 + r) * 64 + d4];
      num[r] += q4.x * kv0 + q4.y * kv1 + q4.z * kv2 + q4.w * kv3;
      den[r] += q4.x * ks4.x + q4.y * ks4.y + q4.z * ks4.z + q4.w * ks4.w;
    }
  }
  #pragma unroll
  for (int r = 0; r < 8; r++) {
    int row = rb * 32 + rg * 8 + r;
    aw[((size_t)(s * KSEG + row)) * 256 + h * 64 + e] = num[r] / (den[r] + 1e-6f);
  }
}

// ---------------- Phase C: fused node MLP (bf16 MFMA) ----------------
#define AP2 264
#define CP2 260
__global__ __launch_bounds__(256, 5) void node_mlp_kernel(
    const float* __restrict__ H, const int* __restrict__ pids,
    const unsigned short* __restrict__ psub,
    const unsigned short* __restrict__ W1f, const unsigned short* __restrict__ W2f,
    const float* __restrict__ b1, const float* __restrict__ b2,
    float* __restrict__ out)
{
  __shared__ __align__(16) unsigned char smem[32 * AP2 * 2];  // 16896 B
  __shared__ int pidl[32];
  unsigned short* Ah = (unsigned short*)smem;
  float* Cl = (float*)smem;
  int tid = threadIdx.x;
  int lane = tid & 63, w = tid >> 6;
  int ln15 = lane & 15, hi = lane >> 4;
  int base = blockIdx.x * 32;

  f32x4 acc[2][4];
  #pragma unroll
  for (int a = 0; a < 2; a++)
    #pragma unroll
    for (int c = 0; c < 4; c++) acc[a][c] = (f32x4){0.f, 0.f, 0.f, 0.f};

  if (tid < 32) pidl[tid] = pids[base + tid];
  for (int i = tid; i < 32 * 64; i += 256) {
    int r = i >> 6, c4 = i & 63;
    float4 f = *(const float4*)(H + ((size_t)(base + r)) * 256 + c4 * 4);
    unsigned int lo = (unsigned int)f2bf(f.x) | ((unsigned int)f2bf(f.y) << 16);
    unsigned int hi2 = (unsigned int)f2bf(f.z) | ((unsigned int)f2bf(f.w) << 16);
    u32x2 val = {lo, hi2};
    *((u32x2*)&Ah[r * AP2 + c4 * 4]) = val;
  }
  __syncthreads();

  const unsigned short* Wl1 = W1f + (size_t)lane * 8;
  {
    short8 bcur[4];
    #pragma unroll
    for (int ct = 0; ct < 4; ct++)
      bcur[ct] = *(const short8*)(Wl1 + ((w * 4 + ct) * 16 + 0) * 512);
    #pragma unroll
    for (int kc = 0; kc < 8; kc++) {
      short8 a[2], bnext[4];
      #pragma unroll
      for (int rt = 0; rt < 2; rt++)
        a[rt] = *(const short8*)(&Ah[(rt * 16 + ln15) * AP2 + kc * 32 + hi * 8]);
      #pragma unroll
      for (int ct = 0; ct < 4; ct++)
        bnext[ct] = *(const short8*)(Wl1 + ((w * 4 + ct) * 16 + kc + 1) * 512);
      __builtin_amdgcn_s_setprio(1);
      #pragma unroll
      for (int rt = 0; rt < 2; rt++)
        #pragma unroll
        for (int ct = 0; ct < 4; ct++)
          acc[rt][ct] = __builtin_amdgcn_mfma_f32_16x16x32_bf16(a[rt], bcur[ct], acc[rt][ct], 0, 0, 0);
      __builtin_amdgcn_s_setprio(0);
      #pragma unroll
      for (int ct = 0; ct < 4; ct++) bcur[ct] = bnext[ct];
    }
  }
  __syncthreads();

  for (int i = tid; i < 32 * 32; i += 256) {
    int r = i >> 5, ch = i & 31;
    int node = base + r;
    int ss = node >> 15;
    int pid = pidl[r];
    *((u32x4*)&Ah[r * AP2 + ch * 8]) =
        *(const u32x4*)(psub + ((size_t)(ss * KSEG + pid)) * 256 + ch * 8);
  }
  __syncthreads();

  {
    short8 bcur[4];
    #pragma unroll
    for (int ct = 0; ct < 4; ct++)
      bcur[ct] = *(const short8*)(Wl1 + ((w * 4 + ct) * 16 + 8) * 512);
    #pragma unroll
    for (int kc = 8; kc < 16; kc++) {
      short8 a[2], bnext[4];
      #pragma unroll
      for (int rt = 0; rt < 2; rt++)
        a[rt] = *(const short8*)(&Ah[(rt * 16 + ln15) * AP2 + (kc - 8) * 32 + hi * 8]);
      if (kc < 15) {
        #pragma unroll
        for (int ct = 0; ct < 4; ct++)
          bnext[ct] = *(const short8*)(Wl1 + ((w * 4 + ct) * 16 + kc + 1) * 512);
      }
      __builtin_amdgcn_s_setprio(1);
      #pragma unroll
      for (int rt = 0; rt < 2; rt++)
        #pragma unroll
        for (int ct = 0; ct < 4; ct++)
          acc[rt][ct] = __builtin_amdgcn_mfma_f32_16x16x32_bf16(a[rt], bcur[ct], acc[rt][ct], 0, 0, 0);
      __builtin_amdgcn_s_setprio(0);
      if (kc < 15) {
        #pragma unroll
        for (int ct = 0; ct < 4; ct++) bcur[ct] = bnext[ct];
      }
    }
  }
  __syncthreads();

  #pragma unroll
  for (int rt = 0; rt < 2; rt++) {
    #pragma unroll
    for (int ct = 0; ct < 4; ct++) {
      int col = w * 64 + ct * 16 + ln15;
      float bb = b1[col];
      #pragma unroll
      for (int r = 0; r < 4; r++) {
        int row = rt * 16 + hi * 4 + r;
        Ah[row * AP2 + col] = f2bf(gelu_f(acc[rt][ct][r] + bb));
      }
      acc[rt][ct] = (f32x4){0.f, 0.f, 0.f, 0.f};
    }
  }
  __syncthreads();

  {
    const unsigned short* Wl2 = W2f + (size_t)lane * 8;
    short8 bcur[4];
    #pragma unroll
    for (int ct = 0; ct < 4; ct++)
      bcur[ct] = *(const short8*)(Wl2 + ((w * 4 + ct) * 8 + 0) * 512);
    #pragma unroll
    for (int kc = 0; kc < 8; kc++) {
      short8 a[2], bnext[4];
      #pragma unroll
      for (int rt = 0; rt < 2; rt++)
        a[rt] = *(const short8*)(&Ah[(rt * 16 + ln15) * AP2 + kc * 32 + hi * 8]);
      if (kc < 7) {
        #pragma unroll
        for (int ct = 0; ct < 4; ct++)
          bnext[ct] = *(const short8*)(Wl2 + ((w * 4 + ct) * 8 + kc + 1) * 512);
      }
      __builtin_amdgcn_s_setprio(1);
      #pragma unroll
      for (int rt = 0; rt < 2; rt++)
        #pragma unroll
        for (int ct = 0; ct < 4; ct++)
          acc[rt][ct] = __builtin_amdgcn_mfma_f32_16x16x32_bf16(a[rt], bcur[ct], acc[rt][ct], 0, 0, 0);
      __builtin_amdgcn_s_setprio(0);
      if (kc < 7) {
        #pragma unroll
        for (int ct = 0; ct < 4; ct++) bcur[ct] = bnext[ct];
      }
    }
  }

  #pragma unroll
  for (int rh = 0; rh < 2; rh++) {
    __syncthreads();
    #pragma unroll
    for (int ct = 0; ct < 4; ct++) {
      int col = w * 64 + ct * 16 + ln15;
      float bb = b2[col];
      #pragma unroll
      for (int r = 0; r < 4; r++)
        Cl[(hi * 4 + r) * CP2 + col] = acc[rh][ct][r] + bb;
    }
    __syncthreads();
    for (int i = tid; i < 16 * 64; i += 256) {
      int r = i >> 6, c4 = i & 63;
      size_t gidx = ((size_t)(base + rh * 16 + r)) * 256 + c4 * 4;
      float4 h4 = *(const float4*)(H + gidx);
      float4 cv = *(const float4*)&Cl[r * CP2 + c4 * 4];
      float4 o4 = {h4.x + cv.x, h4.y + cv.y, h4.z + cv.z, h4.w + cv.w};
      *(float4*)(out + gidx) = o4;
    }
  }
}

extern "C" void kernel_launch(void* const* d_in, const int* in_sizes, int n_in,
                              void* d_out, int out_size, void* d_ws, size_t ws_size,
                              hipStream_t stream) {
  (void)in_sizes; (void)n_in; (void)out_size; (void)ws_size;
  const float* H    = (const float*)d_in[0];
  const int*   pids = (const int*)d_in[1];
  const float* ln1g = (const float*)d_in[2];
  const float* ln1b = (const float*)d_in[3];
  const float* Wq   = (const float*)d_in[4];
  const float* bq   = (const float*)d_in[5];
  const float* Wk   = (const float*)d_in[6];
  const float* bk   = (const float*)d_in[7];
  const float* Wv   = (const float*)d_in[8];
  const float* bv   = (const float*)d_in[9];
  const float* Wo   = (const float*)d_in[10];
  const float* bo   = (const float*)d_in[11];
  const float* ln2g = (const float*)d_in[12];
  const float* ln2b = (const float*)d_in[13];
  const float* fW1  = (const float*)d_in[14];
  const float* fb1  = (const float*)d_in[15];
  const float* fW2  = (const float*)d_in[16];
  const float* fb2  = (const float*)d_in[17];
  const float* mW1  = (const float*)d_in[18];
  const float* mb1  = (const float*)d_in[19];
  const float* mW2  = (const float*)d_in[20];
  const float* mb2  = (const float*)d_in[21];
  float* out = (float*)d_out;
  float* ws = (float*)d_ws;

  int*   histc   = (int*)ws;                          // 0      (32768)
  int*   segstart= (int*)(ws + 32768);                // 32768  (2048)
  int*   cnti    = (int*)(ws + 34816);                // 34816  (2048)
  int*   order   = (int*)(ws + 36864);                // 36864  (131072)
  float* counts  = ws + 167936;                       // (2048)
  float* xw      = ws + 169984;                       // (524288)
  float* yw      = ws + 694272;                       // (524288)
  float* qw      = ws + 1218560;                      // (524288)
  float* kw      = ws + 1742848;                      // (524288)
  float* vw      = ws + 2267136;                      // (524288)
  float* kvb     = ws + 2791424;                      // (65536)
  float* ksb     = ws + 2856960;                      // (1024)
  float* aw      = ws + 2857984;                      // (524288)
  float* x2w     = ws + 3382272;                      // (524288)
  float* y2w     = ws + 3906560;                      // (524288)
  unsigned short* hidb  = (unsigned short*)(ws + 4430848);  // 2M shorts
  unsigned short* psub  = (unsigned short*)(ws + 5479424);  // 512K shorts
  unsigned short* Wpack = (unsigned short*)(ws + 5741568);  // 983040 shorts

  hipMemsetAsync(kvb, 0, (65536 + 1024) * sizeof(float), stream);

  wprep2_kernel<<<480, 256, 0, stream>>>(Wq, Wk, Wv, Wo, fW1, fW2, mW1, mW2, Wpack);
  hist_kernel<<<64, 256, 0, stream>>>(pids, histc);
  prefix_kernel<<<4, 256, 0, stream>>>(histc, segstart, cnti, counts);
  scatter_kernel<<<64, 256, 0, stream>>>(pids, histc, order);
  pool_gather<<<1024, 256, 0, stream>>>(H, order, segstart, cnti, xw);
  pool_ln_kernel<<<2048, 256, 0, stream>>>(xw, ln1g, ln1b, yw);
  qkv_mfma<<<dim3(128, 3), 256, 0, stream>>>(yw, counts, Wpack, bq, bk, bv, qw, kw, vw);
  kv_kernel<<<128, 256, 0, stream>>>(kw, vw, kvb, ksb);
  attn_kernel<<<256, 256, 0, stream>>>(qw, kvb, ksb, aw);
  oproj_mfma<<<128, 256, 0, stream>>>(aw, xw, Wpack, bo, x2w);
  ln_kernel<<<2048, 256, 0, stream>>>(x2w, y2w, ln2g, ln2b);
  ffn1_mfma<<<dim3(128, 4), 256, 0, stream>>>(y2w, Wpack, fb1, hidb);
  ffn2_mfma<<<128, 256, 0, stream>>>(hidb, x2w, Wpack, fb2,
                                     out + (size_t)S * N * D, psub);
  node_mlp_kernel<<<4096, 256, 0, stream>>>(H, pids, psub,
                                            Wpack + 786432, Wpack + 917504,
                                            mb1, mb2, out);
}